// Round 2
// baseline (1696.665 us; speedup 1.0000x reference)
//
#include <hip/hip_runtime.h>
#include <hip/hip_bf16.h>

typedef __bf16 bf16_t;
typedef __bf16 bf16x8 __attribute__((ext_vector_type(8)));
typedef float  f32x4  __attribute__((ext_vector_type(4)));

#define GAS __attribute__((address_space(1)))
#define LAS __attribute__((address_space(3)))

__device__ __forceinline__ void gload_lds16(const bf16_t* g, bf16_t* l) {
    __builtin_amdgcn_global_load_lds((const GAS void*)g, (LAS void*)l, 16, 0, 0);
}

__device__ __forceinline__ unsigned short f2bf_bits(float f) {
    bf16_t h = (bf16_t)f;
    return __builtin_bit_cast(unsigned short, h);
}

// ---------------- split fp32 -> (hi, lo) bf16 ----------------
__global__ __launch_bounds__(256) void k_split_x(const float* __restrict__ X,
                                                 bf16_t* __restrict__ H,
                                                 bf16_t* __restrict__ L, int n) {
    int i = (blockIdx.x * 256 + threadIdx.x) * 4;
    if (i >= n) return;
    float4 v = *(const float4*)(X + i);
    float vv[4] = {v.x, v.y, v.z, v.w};
    union { bf16_t b[4]; uint2 u; } hh, ll;
#pragma unroll
    for (int j = 0; j < 4; j++) {
        bf16_t h = (bf16_t)vv[j];
        hh.b[j] = h;
        ll.b[j] = (bf16_t)(vv[j] - (float)h);
    }
    *(uint2*)(H + i) = hh.u;
    *(uint2*)(L + i) = ll.u;
}

// ---------------- W[3,512,512] -> WT[3,512(o),512(d)] split ----------------
__global__ __launch_bounds__(256) void k_split_wt(const float* __restrict__ W,
                                                  bf16_t* __restrict__ H,
                                                  bf16_t* __restrict__ L) {
    int t = blockIdx.x * 256 + threadIdx.x;  // 196608 threads, 4 elems each
    int base = t * 4;
    int m = base >> 18;
    int o = (base >> 9) & 511;
    int d = base & 511;
    union { bf16_t b[4]; uint2 u; } hh, ll;
#pragma unroll
    for (int j = 0; j < 4; j++) {
        float w = W[m * 262144 + (d + j) * 512 + o];
        bf16_t h = (bf16_t)w;
        hh.b[j] = h;
        ll.b[j] = (bf16_t)(w - (float)h);
    }
    *(uint2*)(H + base) = hh.u;
    *(uint2*)(L + base) = ll.u;
}

// ---------------- V [2048][512] -> VT [512][2048] (single batch) ----------
__global__ __launch_bounds__(256) void k_transpose_v(const bf16_t* __restrict__ V,
                                                     bf16_t* __restrict__ VT) {
    __shared__ bf16_t tile[32][33];
    const int tx = threadIdx.x;  // 32
    const int ty = threadIdx.y;  // 8
    const int n0 = blockIdx.x * 32, o0 = blockIdx.y * 32;
#pragma unroll
    for (int i = 0; i < 4; i++)
        tile[ty + i * 8][tx] = V[(size_t)(n0 + ty + i * 8) * 512 + o0 + tx];
    __syncthreads();
#pragma unroll
    for (int i = 0; i < 4; i++)
        VT[(size_t)(o0 + ty + i * 8) * 2048 + n0 + tx] = tile[tx][ty + i * 8];
}

// ---------------- GEMM-NT, 128x128 tile, BK=32, 4 waves (2x2) ----------------
// C[i,j] = sum_k A[i,k]*B[j,k].  SPLIT: A,B given as (hi,lo) bf16 pairs,
// acc += Ah*Bh + Ah*Bl + Al*Bh  (bf16x3 ~ fp32 precision).
// EPI 0: QKV epilogue (write Qh/Ql, Kh/Kl, V bf16 by column group)
// EPI 1: C = acc * scale (fp32)
// EPI 2: plain bf16 input (no split), C = acc (fp32)
template <int EPI>
__global__ __launch_bounds__(256) void k_gemm_nt(
    const bf16_t* __restrict__ Ah, const bf16_t* __restrict__ Al,
    const bf16_t* __restrict__ Bh, const bf16_t* __restrict__ Bl,
    int lda, int ldb, int K,
    float* __restrict__ Cf, float scale, int ldc,
    bf16_t* __restrict__ Qh, bf16_t* __restrict__ Ql,
    bf16_t* __restrict__ Kh, bf16_t* __restrict__ Kl,
    bf16_t* __restrict__ Vb) {
    constexpr bool SPLIT = (EPI != 2);
    __shared__ bf16_t lds[SPLIT ? 16384 : 8192];
    bf16_t* As_h = lds;
    bf16_t* Bs_h = lds + 4096;
    bf16_t* As_l = SPLIT ? (lds + 8192) : lds;
    bf16_t* Bs_l = SPLIT ? (lds + 12288) : lds;

    const int tid = threadIdx.x;
    const int lane = tid & 63;
    const int wid = tid >> 6;
    const int wr = wid >> 1, wc = wid & 1;
    const size_t i0 = (size_t)blockIdx.y * 128;
    const size_t j0 = (size_t)blockIdx.x * 128;

    const bf16_t* pAh = Ah + i0 * lda;
    const bf16_t* pBh = Bh + j0 * ldb;
    const bf16_t* pAl = SPLIT ? (Al + i0 * lda) : pAh;
    const bf16_t* pBl = SPLIT ? (Bl + j0 * ldb) : pBh;

    const int srow = tid >> 2;           // 0..63
    const int scoff = (tid & 3) * 8;     // 0,8,16,24

    f32x4 acc[4][4] = {};

    const int arow = wr * 64 + (lane & 15);
    const int brow = wc * 64 + (lane & 15);
    const int ko = (lane >> 4) * 8;

    for (int kt = 0; kt < K; kt += 32) {
#pragma unroll
        for (int c = 0; c < 2; c++) {
            const size_t ra = (size_t)(c * 64 + srow) * lda + kt + scoff;
            const size_t rb = (size_t)(c * 64 + srow) * ldb + kt + scoff;
            const int loff = c * 2048 + tid * 8;
            gload_lds16(pAh + ra, As_h + loff);
            gload_lds16(pBh + rb, Bs_h + loff);
            if (SPLIT) {
                gload_lds16(pAl + ra, As_l + loff);
                gload_lds16(pBl + rb, Bs_l + loff);
            }
        }
        __syncthreads();

        bf16x8 ah[4], bh[4];
#pragma unroll
        for (int m = 0; m < 4; m++) ah[m] = *(const bf16x8*)&As_h[(arow + m * 16) * 32 + ko];
#pragma unroll
        for (int n = 0; n < 4; n++) bh[n] = *(const bf16x8*)&Bs_h[(brow + n * 16) * 32 + ko];
        if (SPLIT) {
            bf16x8 al[4], bl[4];
#pragma unroll
            for (int m = 0; m < 4; m++) al[m] = *(const bf16x8*)&As_l[(arow + m * 16) * 32 + ko];
#pragma unroll
            for (int n = 0; n < 4; n++) bl[n] = *(const bf16x8*)&Bs_l[(brow + n * 16) * 32 + ko];
#pragma unroll
            for (int m = 0; m < 4; m++)
#pragma unroll
                for (int n = 0; n < 4; n++) {
                    acc[m][n] = __builtin_amdgcn_mfma_f32_16x16x32_bf16(ah[m], bh[n], acc[m][n], 0, 0, 0);
                    acc[m][n] = __builtin_amdgcn_mfma_f32_16x16x32_bf16(ah[m], bl[n], acc[m][n], 0, 0, 0);
                    acc[m][n] = __builtin_amdgcn_mfma_f32_16x16x32_bf16(al[m], bh[n], acc[m][n], 0, 0, 0);
                }
        } else {
#pragma unroll
            for (int m = 0; m < 4; m++)
#pragma unroll
                for (int n = 0; n < 4; n++)
                    acc[m][n] = __builtin_amdgcn_mfma_f32_16x16x32_bf16(ah[m], bh[n], acc[m][n], 0, 0, 0);
        }
        __syncthreads();
    }

#pragma unroll
    for (int m = 0; m < 4; m++) {
#pragma unroll
        for (int n = 0; n < 4; n++) {
#pragma unroll
            for (int j = 0; j < 4; j++) {
                const size_t gr = i0 + wr * 64 + m * 16 + (lane >> 4) * 4 + j;
                const size_t gc = j0 + wc * 64 + n * 16 + (lane & 15);
                float v = acc[m][n][j];
                if (EPI == 0) {
                    const int mat = (int)(gc >> 9);
                    const size_t idx = gr * 512 + (gc & 511);
                    if (mat == 0) {
                        bf16_t h = (bf16_t)v;
                        Qh[idx] = h; Ql[idx] = (bf16_t)(v - (float)h);
                    } else if (mat == 1) {
                        bf16_t h = (bf16_t)v;
                        Kh[idx] = h; Kl[idx] = (bf16_t)(v - (float)h);
                    } else {
                        Vb[idx] = (bf16_t)v;
                    }
                } else if (EPI == 1) {
                    Cf[gr * (size_t)ldc + gc] = v * scale;
                } else {
                    Cf[gr * (size_t)ldc + gc] = v;
                }
            }
        }
    }
}

// ---------------- row softmax, in place: fp32 row (2048) -> bf16 row -------
// Row r of S occupies 8192 B; bf16 P row written over its first 4096 B,
// i.e. P has element pitch 4096 when viewed as bf16.
__global__ __launch_bounds__(256) void k_softmax(float* __restrict__ S) {
    const int row = blockIdx.x;
    float* srow = S + (size_t)row * 2048;
    const int t = threadIdx.x;
    const int lane = t & 63, wid = t >> 6;
    __shared__ float redm[4], reds[4];

    float4 v0 = ((const float4*)srow)[t];
    float4 v1 = ((const float4*)srow)[t + 256];
    float mx = fmaxf(fmaxf(fmaxf(v0.x, v0.y), fmaxf(v0.z, v0.w)),
                     fmaxf(fmaxf(v1.x, v1.y), fmaxf(v1.z, v1.w)));
#pragma unroll
    for (int o = 1; o < 64; o <<= 1) mx = fmaxf(mx, __shfl_xor(mx, o));
    if (lane == 0) redm[wid] = mx;
    __syncthreads();
    mx = fmaxf(fmaxf(redm[0], redm[1]), fmaxf(redm[2], redm[3]));

    float e[8];
    e[0] = expf(v0.x - mx); e[1] = expf(v0.y - mx);
    e[2] = expf(v0.z - mx); e[3] = expf(v0.w - mx);
    e[4] = expf(v1.x - mx); e[5] = expf(v1.y - mx);
    e[6] = expf(v1.z - mx); e[7] = expf(v1.w - mx);
    float s = (e[0] + e[1] + e[2] + e[3]) + (e[4] + e[5] + e[6] + e[7]);
#pragma unroll
    for (int o = 1; o < 64; o <<= 1) s += __shfl_xor(s, o);
    if (lane == 0) reds[wid] = s;
    __syncthreads();
    s = reds[0] + reds[1] + reds[2] + reds[3];
    const float inv = 1.0f / s;

    ushort4 p0, p1;
    p0.x = f2bf_bits(e[0] * inv); p0.y = f2bf_bits(e[1] * inv);
    p0.z = f2bf_bits(e[2] * inv); p0.w = f2bf_bits(e[3] * inv);
    p1.x = f2bf_bits(e[4] * inv); p1.y = f2bf_bits(e[5] * inv);
    p1.z = f2bf_bits(e[6] * inv); p1.w = f2bf_bits(e[7] * inv);
    ((ushort4*)srow)[t] = p0;
    ((ushort4*)srow)[t + 256] = p1;
}

extern "C" void kernel_launch(void* const* d_in, const int* in_sizes, int n_in,
                              void* d_out, int out_size, void* d_ws, size_t ws_size,
                              hipStream_t stream) {
    const float* x = (const float*)d_in[0];
    const float* w = (const float*)d_in[1];
    float* out = (float*)d_out;

    const size_t NB = (size_t)2048 * 512;     // per-batch Q/K/V elems (1 M)
    const size_t NW = (size_t)3 * 512 * 512;  // 786432

    size_t off = 0;
    char* wsb = (char*)d_ws;
    auto take = [&](size_t bytes) -> char* {
        char* p = wsb + off;
        off = (off + bytes + 255) & ~(size_t)255;
        return p;
    };
    // persistent: split W^T (3 MB)
    bf16_t* wth = (bf16_t*)take(NW * 2);
    bf16_t* wtl = (bf16_t*)take(NW * 2);
    // per-batch reusable buffers (2 MB each, 16 MB total)
    bf16_t* xh = (bf16_t*)take(NB * 2);
    bf16_t* xl = (bf16_t*)take(NB * 2);
    bf16_t* qh = (bf16_t*)take(NB * 2);
    bf16_t* ql = (bf16_t*)take(NB * 2);
    bf16_t* kh = (bf16_t*)take(NB * 2);
    bf16_t* kl = (bf16_t*)take(NB * 2);
    bf16_t* vb = (bf16_t*)take(NB * 2);
    bf16_t* vt = (bf16_t*)take(NB * 2);

    // scores chunk: CH Q-rows of fp32[2048], CH multiple of 128, max 2048
    size_t rem = ws_size > off ? ws_size - off : 0;
    size_t ch_rows = (rem / ((size_t)2048 * 4)) & ~(size_t)127;
    if (ch_rows > 2048) ch_rows = 2048;
    if (ch_rows < 128) return;  // < ~21 MB workspace: cannot run
    const int CH = (int)ch_rows;
    float* S = (float*)take((size_t)CH * 2048 * 4);

    k_split_wt<<<dim3((unsigned)(NW / 4 / 256)), 256, 0, stream>>>(w, wth, wtl);

    const float scale = 0.044194173824159216f;  // 1/sqrt(512)
    for (int b = 0; b < 16; b++) {
        const size_t xoff = (size_t)b * NB;
        // split this batch's x
        k_split_x<<<dim3((unsigned)(NB / 4 / 256)), 256, 0, stream>>>(
            x + xoff, xh, xl, (int)NB);
        // QKV: [2048 x 1536] = x[2048 x 512] @ WT[1536 x 512]^T, 3-pass split
        k_gemm_nt<0><<<dim3(12, 16, 1), 256, 0, stream>>>(
            xh, xl, wth, wtl, 512, 512, 512,
            nullptr, 1.0f, 0, qh, ql, kh, kl, vb);
        // V -> VT
        k_transpose_v<<<dim3(64, 16, 1), dim3(32, 8), 0, stream>>>(vb, vt);

        for (int q0 = 0; q0 < 2048; q0 += CH) {
            const int cb = (2048 - q0 < CH) ? (2048 - q0) : CH;
            // scores: [cb x 2048] = Q[cb x 512] @ K[2048 x 512]^T * scale
            k_gemm_nt<1><<<dim3(16, cb / 128, 1), 256, 0, stream>>>(
                qh + (size_t)q0 * 512, ql + (size_t)q0 * 512, kh, kl,
                512, 512, 512,
                S, scale, 2048, nullptr, nullptr, nullptr, nullptr, nullptr);
            // softmax rows (in-place fp32 -> bf16, pitch 4096 elems)
            k_softmax<<<dim3(cb), 256, 0, stream>>>(S);
            // out rows: [cb x 512] = P[cb x 2048] @ VT[512 x 2048]^T
            k_gemm_nt<2><<<dim3(4, cb / 128, 1), 256, 0, stream>>>(
                (const bf16_t*)S, nullptr, vt, nullptr, 4096, 2048, 2048,
                out + xoff + (size_t)q0 * 512, 1.0f, 512,
                nullptr, nullptr, nullptr, nullptr, nullptr);
        }
    }
}

// Round 4
// 760.968 us; speedup vs baseline: 2.2296x; 2.2296x over previous
//
#include <hip/hip_runtime.h>
#include <hip/hip_bf16.h>

typedef __bf16 bf16_t;
typedef __bf16 bf16x8 __attribute__((ext_vector_type(8)));
typedef float  f32x4  __attribute__((ext_vector_type(4)));

#define GAS __attribute__((address_space(1)))
#define LAS __attribute__((address_space(3)))

__device__ __forceinline__ void gload_lds16(const bf16_t* g, bf16_t* l) {
    __builtin_amdgcn_global_load_lds((const GAS void*)g, (LAS void*)l, 16, 0, 0);
}

#define QSCALE 0.044194173824159216f  /* 1/sqrt(512) */
#define L2E    1.4426950408889634f

// ---------------- split fp32 -> (hi, lo) bf16 ----------------
__global__ __launch_bounds__(256) void k_split_x(const float* __restrict__ X,
                                                 bf16_t* __restrict__ H,
                                                 bf16_t* __restrict__ L, int n) {
    int i = (blockIdx.x * 256 + threadIdx.x) * 4;
    if (i >= n) return;
    float4 v = *(const float4*)(X + i);
    float vv[4] = {v.x, v.y, v.z, v.w};
    union { bf16_t b[4]; uint2 u; } hh, ll;
#pragma unroll
    for (int j = 0; j < 4; j++) {
        bf16_t h = (bf16_t)vv[j];
        hh.b[j] = h;
        ll.b[j] = (bf16_t)(vv[j] - (float)h);
    }
    *(uint2*)(H + i) = hh.u;
    *(uint2*)(L + i) = ll.u;
}

// ---------------- W[3,512,512] -> WT[3,512(o),512(d)] split ----------------
__global__ __launch_bounds__(256) void k_split_wt(const float* __restrict__ W,
                                                  bf16_t* __restrict__ H,
                                                  bf16_t* __restrict__ L) {
    int t = blockIdx.x * 256 + threadIdx.x;
    int base = t * 4;
    int m = base >> 18;
    int o = (base >> 9) & 511;
    int d = base & 511;
    union { bf16_t b[4]; uint2 u; } hh, ll;
#pragma unroll
    for (int j = 0; j < 4; j++) {
        float w = W[m * 262144 + (d + j) * 512 + o];
        bf16_t h = (bf16_t)w;
        hh.b[j] = h;
        ll.b[j] = (bf16_t)(w - (float)h);
    }
    *(uint2*)(H + base) = hh.u;
    *(uint2*)(L + base) = ll.u;
}

// -------- QKV projection GEMM-NT, 128x128 tile, BK=32, split bf16x3 --------
// A = x split [2048G x 512]; B = WT split [1536 x 512]. Epilogue:
//   cols 0..511   -> Q*QSCALE split -> Qh/Ql
//   cols 512..1023-> K split        -> Kh/Kl
//   cols 1024..   -> V bf16 written TRANSPOSED into VT[b][512(o)][2048(n)]
__global__ __launch_bounds__(256) void k_qkv(
    const bf16_t* __restrict__ Ah, const bf16_t* __restrict__ Al,
    const bf16_t* __restrict__ Bh, const bf16_t* __restrict__ Bl,
    bf16_t* __restrict__ Qh, bf16_t* __restrict__ Ql,
    bf16_t* __restrict__ Kh, bf16_t* __restrict__ Kl,
    bf16_t* __restrict__ VT) {
    __shared__ bf16_t lds[16384];
    bf16_t* As_h = lds;
    bf16_t* Bs_h = lds + 4096;
    bf16_t* As_l = lds + 8192;
    bf16_t* Bs_l = lds + 12288;

    const int tid = threadIdx.x;
    const int lane = tid & 63;
    const int wid = tid >> 6;
    const int wr = wid >> 1, wc = wid & 1;
    const size_t i0 = (size_t)blockIdx.y * 128;
    const size_t j0 = (size_t)blockIdx.x * 128;

    const bf16_t* pAh = Ah + i0 * 512;
    const bf16_t* pBh = Bh + j0 * 512;
    const bf16_t* pAl = Al + i0 * 512;
    const bf16_t* pBl = Bl + j0 * 512;

    const int srow = tid >> 2;
    const int scoff = (tid & 3) * 8;

    f32x4 acc[4][4] = {};

    const int arow = wr * 64 + (lane & 15);
    const int brow = wc * 64 + (lane & 15);
    const int ko = (lane >> 4) * 8;

    for (int kt = 0; kt < 512; kt += 32) {
#pragma unroll
        for (int c = 0; c < 2; c++) {
            // row-relative offset: identical for A and B panels (lda == ldb == 512)
            const size_t ra = (size_t)(c * 64 + srow) * 512 + kt + scoff;
            const int loff = c * 2048 + tid * 8;
            gload_lds16(pAh + ra, As_h + loff);
            gload_lds16(pBh + ra, Bs_h + loff);
            gload_lds16(pAl + ra, As_l + loff);
            gload_lds16(pBl + ra, Bs_l + loff);
        }
        __syncthreads();

        bf16x8 ah[4], bh[4], al[4], bl[4];
#pragma unroll
        for (int m = 0; m < 4; m++) ah[m] = *(const bf16x8*)&As_h[(arow + m * 16) * 32 + ko];
#pragma unroll
        for (int n = 0; n < 4; n++) bh[n] = *(const bf16x8*)&Bs_h[(brow + n * 16) * 32 + ko];
#pragma unroll
        for (int m = 0; m < 4; m++) al[m] = *(const bf16x8*)&As_l[(arow + m * 16) * 32 + ko];
#pragma unroll
        for (int n = 0; n < 4; n++) bl[n] = *(const bf16x8*)&Bs_l[(brow + n * 16) * 32 + ko];
#pragma unroll
        for (int m = 0; m < 4; m++)
#pragma unroll
            for (int n = 0; n < 4; n++) {
                acc[m][n] = __builtin_amdgcn_mfma_f32_16x16x32_bf16(ah[m], bh[n], acc[m][n], 0, 0, 0);
                acc[m][n] = __builtin_amdgcn_mfma_f32_16x16x32_bf16(ah[m], bl[n], acc[m][n], 0, 0, 0);
                acc[m][n] = __builtin_amdgcn_mfma_f32_16x16x32_bf16(al[m], bh[n], acc[m][n], 0, 0, 0);
            }
        __syncthreads();
    }

#pragma unroll
    for (int m = 0; m < 4; m++) {
#pragma unroll
        for (int n = 0; n < 4; n++) {
#pragma unroll
            for (int j = 0; j < 4; j++) {
                const size_t gr = i0 + wr * 64 + m * 16 + (lane >> 4) * 4 + j;
                const size_t gc = j0 + wc * 64 + n * 16 + (lane & 15);
                float v = acc[m][n][j];
                const int mat = (int)(gc >> 9);
                const size_t bloc = gr >> 11;
                const size_t nrow = gr & 2047;
                const size_t o = gc & 511;
                const size_t idx = bloc * 1048576 + nrow * 512 + o;
                if (mat == 0) {
                    float v2 = v * QSCALE;
                    bf16_t h = (bf16_t)v2;
                    Qh[idx] = h; Ql[idx] = (bf16_t)(v2 - (float)h);
                } else if (mat == 1) {
                    bf16_t h = (bf16_t)v;
                    Kh[idx] = h; Kl[idx] = (bf16_t)(v - (float)h);
                } else {
                    VT[bloc * 1048576 + o * 2048 + nrow] = (bf16_t)v;
                }
            }
        }
    }
}

// ---------------- fused flash attention ----------------
// Grid (32, G). Block 512 thr / 8 waves. QBLK=64 rows, KV tiles of 64.
// QK^T roles: wave = (rg4 = wid>>1 rows, kg = wid&1 kv-half)
// PV   roles: wave = (rg2 = wid>>2 rows, cg = wid&3 col-quarter)
// LDS: QK chunk dbuf 2x32KB | VT tile 64KB | P tile 8KB | mpart/spart/mrow
#define QK0_OFF 0
#define VT_OFF  65536
#define PT_OFF  131072
#define MP_OFF  139264
#define SP_OFF  139776
#define MR_OFF  140288

__global__ __launch_bounds__(512) void k_flash(
    const bf16_t* __restrict__ Qh, const bf16_t* __restrict__ Ql,
    const bf16_t* __restrict__ Kh, const bf16_t* __restrict__ Kl,
    const bf16_t* __restrict__ VT, float* __restrict__ Out) {
    __shared__ __align__(16) char smem[140800];

    const int tid = threadIdx.x;
    const int l = tid & 63, wid = tid >> 6;
    const int l15 = l & 15, l4 = l >> 4;
    const int rg4 = wid >> 1, kg = wid & 1;
    const int rg2 = wid >> 2, cg = wid & 3;
    const int b = blockIdx.y;
    const int q0 = blockIdx.x * 64;
    const size_t NB = 1048576;

    const bf16_t* qhb = Qh + (size_t)b * NB;
    const bf16_t* qlb = Ql + (size_t)b * NB;
    const bf16_t* khb = Kh + (size_t)b * NB;
    const bf16_t* klb = Kl + (size_t)b * NB;
    const bf16_t* vtb = VT + (size_t)b * NB;

    float* MP = (float*)(smem + MP_OFF);   // [2][64] tile-max partials
    float* SP = (float*)(smem + SP_OFF);   // [2][64] exp-sum partials
    float* MR = (float*)(smem + MR_OFF);   // [2][64] running max, ping-pong

    if (tid < 128) MR[tid] = -3e38f;

    f32x4 O[2][8] = {};            // [mf][nf] 16-row x 16-col frags
    float mreg[2][4], lreg[2][4];
#pragma unroll
    for (int mf = 0; mf < 2; mf++)
#pragma unroll
        for (int j = 0; j < 4; j++) { mreg[mf][j] = -3e38f; lreg[mf][j] = 0.f; }

    const int srow = tid >> 3;          // staging row 0..63
    const int sgl = (tid & 7) ^ (srow & 7);  // swizzled source granule
    const int gsw = l15 & 7;            // frag-read swizzle key

    // stage one QK k-chunk (kc of 8) for kv-tile t into buffer b2
    auto stage_chunk = [&](int t, int kc, int b2) {
        const int co = kc * 64 + sgl * 8;
        const bf16_t* qs = qhb + (size_t)(q0 + srow) * 512 + co;
        const bf16_t* qs2 = qlb + (size_t)(q0 + srow) * 512 + co;
        const bf16_t* ks = khb + (size_t)(t * 64 + srow) * 512 + co;
        const bf16_t* ks2 = klb + (size_t)(t * 64 + srow) * 512 + co;
        bf16_t* d = (bf16_t*)(smem + QK0_OFF + b2 * 32768 + tid * 16);
        gload_lds16(qs, d);
        gload_lds16(qs2, d + 4096);
        gload_lds16(ks, d + 8192);
        gload_lds16(ks2, d + 12288);
    };
    // stage V^T eighth j (of 8) for kv-tile t
    auto stage_v = [&](int t, int j) {
        const int g = j * 512 + tid;
        const int orow = g >> 3;
        const int gl = (g & 7) ^ (orow & 7);
        gload_lds16(vtb + (size_t)orow * 2048 + t * 64 + gl * 8,
                    (bf16_t*)(smem + VT_OFF + g * 16));
    };

    stage_chunk(0, 0, 0);

    for (int t = 0; t < 32; t++) {
        f32x4 S[2] = {};
#pragma unroll
        for (int kc = 0; kc < 8; kc++) {
            if (kc == 0)      asm volatile("s_waitcnt vmcnt(0) lgkmcnt(0)" ::: "memory");
            else if (kc == 7) asm volatile("s_waitcnt vmcnt(2)" ::: "memory");
            else              asm volatile("s_waitcnt vmcnt(1)" ::: "memory");
            asm volatile("s_barrier" ::: "memory");
            if (kc < 7) {
                stage_chunk(t, kc + 1, (kc + 1) & 1);
                stage_v(t, kc);
                if (kc == 6) stage_v(t, 7);
            } else if (t < 31) {
                stage_chunk(t + 1, 0, 0);
            }
            // compute chunk kc from buf kc&1
            const char* CB = smem + QK0_OFF + (kc & 1) * 32768;
            const int arow = rg4 * 16 + l15;
#pragma unroll
            for (int ks = 0; ks < 2; ks++) {
                const int gph = ((ks * 4 + l4) ^ gsw) << 4;
                bf16x8 ah = *(const bf16x8*)(CB + arow * 128 + gph);
                bf16x8 al = *(const bf16x8*)(CB + 8192 + arow * 128 + gph);
#pragma unroll
                for (int nf = 0; nf < 2; nf++) {
                    const int brow = kg * 32 + nf * 16 + l15;
                    bf16x8 bh = *(const bf16x8*)(CB + 16384 + brow * 128 + gph);
                    bf16x8 bl = *(const bf16x8*)(CB + 24576 + brow * 128 + gph);
                    S[nf] = __builtin_amdgcn_mfma_f32_16x16x32_bf16(ah, bh, S[nf], 0, 0, 0);
                    S[nf] = __builtin_amdgcn_mfma_f32_16x16x32_bf16(ah, bl, S[nf], 0, 0, 0);
                    S[nf] = __builtin_amdgcn_mfma_f32_16x16x32_bf16(al, bh, S[nf], 0, 0, 0);
                }
            }
        }

        // ---- online softmax (cross-wave via LDS) ----
        const int rb4 = rg4 * 16 + l4 * 4;
        float pm[4];
#pragma unroll
        for (int j = 0; j < 4; j++) pm[j] = fmaxf(S[0][j], S[1][j]);
#pragma unroll
        for (int off = 1; off < 16; off <<= 1)
#pragma unroll
            for (int j = 0; j < 4; j++) pm[j] = fmaxf(pm[j], __shfl_xor(pm[j], off));
        if (l15 == 0) {
            f32x4 v; v[0] = pm[0]; v[1] = pm[1]; v[2] = pm[2]; v[3] = pm[3];
            *(f32x4*)(MP + kg * 64 + rb4) = v;
        }
        asm volatile("s_waitcnt lgkmcnt(0)" ::: "memory");
        asm volatile("s_barrier" ::: "memory");

        f32x4 mp0 = *(const f32x4*)(MP + rb4);
        f32x4 mp1 = *(const f32x4*)(MP + 64 + rb4);
        f32x4 mold = *(const f32x4*)(MR + (t & 1) * 64 + rb4);
        float mnew[4];
#pragma unroll
        for (int j = 0; j < 4; j++) mnew[j] = fmaxf(mold[j], fmaxf(mp0[j], mp1[j]));
        if (kg == 0 && l15 == 0) {
            f32x4 v; v[0] = mnew[0]; v[1] = mnew[1]; v[2] = mnew[2]; v[3] = mnew[3];
            *(f32x4*)(MR + ((t + 1) & 1) * 64 + rb4) = v;
        }
        float p[2][4], ps[4];
#pragma unroll
        for (int nf = 0; nf < 2; nf++)
#pragma unroll
            for (int j = 0; j < 4; j++) p[nf][j] = exp2f((S[nf][j] - mnew[j]) * L2E);
#pragma unroll
        for (int j = 0; j < 4; j++) ps[j] = p[0][j] + p[1][j];
#pragma unroll
        for (int off = 1; off < 16; off <<= 1)
#pragma unroll
            for (int j = 0; j < 4; j++) ps[j] += __shfl_xor(ps[j], off);
        if (l15 == 0) {
            f32x4 v; v[0] = ps[0]; v[1] = ps[1]; v[2] = ps[2]; v[3] = ps[3];
            *(f32x4*)(SP + kg * 64 + rb4) = v;
        }
        // P -> bf16 into swizzled LDS tile
#pragma unroll
        for (int nf = 0; nf < 2; nf++)
#pragma unroll
            for (int j = 0; j < 4; j++) {
                const int row = rb4 + j;
                const int phys = (kg * 4 + nf * 2 + (l15 >> 3)) ^ (row & 7);
                *(bf16_t*)(smem + PT_OFF + row * 128 + phys * 16 + (l15 & 7) * 2) =
                    (bf16_t)p[nf][j];
            }
        if (t < 31) asm volatile("s_waitcnt vmcnt(4) lgkmcnt(0)" ::: "memory");
        else        asm volatile("s_waitcnt vmcnt(0) lgkmcnt(0)" ::: "memory");
        asm volatile("s_barrier" ::: "memory");

        // ---- PV: rescale O, accumulate P*V ----
#pragma unroll
        for (int mf = 0; mf < 2; mf++) {
            const int rb = rg2 * 32 + mf * 16 + l4 * 4;
            f32x4 mn = *(const f32x4*)(MR + ((t + 1) & 1) * 64 + rb);
            f32x4 sp0 = *(const f32x4*)(SP + rb);
            f32x4 sp1 = *(const f32x4*)(SP + 64 + rb);
            float fr[4];
#pragma unroll
            for (int j = 0; j < 4; j++) {
                fr[j] = exp2f((mreg[mf][j] - mn[j]) * L2E);
                lreg[mf][j] = lreg[mf][j] * fr[j] + sp0[j] + sp1[j];
                mreg[mf][j] = mn[j];
            }
#pragma unroll
            for (int nf = 0; nf < 8; nf++)
#pragma unroll
                for (int j = 0; j < 4; j++) O[mf][nf][j] *= fr[j];
        }
#pragma unroll
        for (int ks = 0; ks < 2; ks++) {
            const int gph = ((ks * 4 + l4) ^ gsw) << 4;
            bf16x8 pa[2];
#pragma unroll
            for (int mf = 0; mf < 2; mf++) {
                const int prow = rg2 * 32 + mf * 16 + l15;
                pa[mf] = *(const bf16x8*)(smem + PT_OFF + prow * 128 + gph);
            }
#pragma unroll
            for (int nf = 0; nf < 8; nf++) {
                const int vrow = cg * 128 + nf * 16 + l15;
                bf16x8 vb = *(const bf16x8*)(smem + VT_OFF + vrow * 128 + gph);
#pragma unroll
                for (int mf = 0; mf < 2; mf++)
                    O[mf][nf] = __builtin_amdgcn_mfma_f32_16x16x32_bf16(pa[mf], vb, O[mf][nf], 0, 0, 0);
            }
        }
    }

    // ---- epilogue: O / l ----
#pragma unroll
    for (int mf = 0; mf < 2; mf++) {
        float inv[4];
#pragma unroll
        for (int j = 0; j < 4; j++) inv[j] = 1.0f / lreg[mf][j];
#pragma unroll
        for (int nf = 0; nf < 8; nf++)
#pragma unroll
            for (int j = 0; j < 4; j++) {
                const size_t row = q0 + rg2 * 32 + mf * 16 + l4 * 4 + j;
                const size_t col = cg * 128 + nf * 16 + l15;
                Out[(size_t)b * NB + row * 512 + col] = O[mf][nf][j] * inv[j];
            }
    }
}

extern "C" void kernel_launch(void* const* d_in, const int* in_sizes, int n_in,
                              void* d_out, int out_size, void* d_ws, size_t ws_size,
                              hipStream_t stream) {
    const float* x = (const float*)d_in[0];
    const float* w = (const float*)d_in[1];
    float* out = (float*)d_out;

    const size_t NB = (size_t)2048 * 512;     // per-batch Q/K/V elems
    const size_t NW = (size_t)3 * 512 * 512;

    // group size: per-group footprint = 7 bufs x 2MB x G; persistent W split 3MB
    const size_t perG = 7 * NB * 2;
    size_t fixed = 2 * NW * 2 + 4096;
    int G = 1;
    if (ws_size > fixed + perG) {
        size_t g = (ws_size - fixed) / perG;
        G = (int)(g > 16 ? 16 : g);
    } else {
        return;  // workspace too small (needs ~17 MB)
    }

    size_t off = 0;
    char* wsb = (char*)d_ws;
    auto take = [&](size_t bytes) -> char* {
        char* p = wsb + off;
        off = (off + bytes + 255) & ~(size_t)255;
        return p;
    };
    bf16_t* wth = (bf16_t*)take(NW * 2);
    bf16_t* wtl = (bf16_t*)take(NW * 2);
    bf16_t* xh = (bf16_t*)take(G * NB * 2);
    bf16_t* xl = (bf16_t*)take(G * NB * 2);
    bf16_t* qh = (bf16_t*)take(G * NB * 2);
    bf16_t* ql = (bf16_t*)take(G * NB * 2);
    bf16_t* kh = (bf16_t*)take(G * NB * 2);
    bf16_t* kl = (bf16_t*)take(G * NB * 2);
    bf16_t* vt = (bf16_t*)take(G * NB * 2);

    k_split_wt<<<dim3((unsigned)(NW / 4 / 256)), 256, 0, stream>>>(w, wth, wtl);

    for (int g0 = 0; g0 < 16; g0 += G) {
        const int Gc = (16 - g0 < G) ? (16 - g0) : G;
        const size_t base = (size_t)g0 * NB;
        k_split_x<<<dim3((unsigned)(Gc * NB / 4 / 256)), 256, 0, stream>>>(
            x + base, xh, xl, (int)(Gc * NB));
        k_qkv<<<dim3(12, 16 * Gc), 256, 0, stream>>>(
            xh, xl, wth, wtl, qh, ql, kh, kl, vt);
        k_flash<<<dim3(32, Gc), 512, 0, stream>>>(
            qh, ql, kh, kl, vt, out + base);
    }
}

// Round 5
// 731.657 us; speedup vs baseline: 2.3189x; 1.0401x over previous
//
#include <hip/hip_runtime.h>
#include <hip/hip_bf16.h>

typedef __bf16 bf16_t;
typedef __bf16 bf16x8 __attribute__((ext_vector_type(8)));
typedef float  f32x4  __attribute__((ext_vector_type(4)));

#define GAS __attribute__((address_space(1)))
#define LAS __attribute__((address_space(3)))

__device__ __forceinline__ void gload_lds16(const bf16_t* g, bf16_t* l) {
    __builtin_amdgcn_global_load_lds((const GAS void*)g, (LAS void*)l, 16, 0, 0);
}

#define QSCALE 0.044194173824159216f  /* 1/sqrt(512) */
#define L2E    1.4426950408889634f

// ---------------- split fp32 -> (hi, lo) bf16 ----------------
__global__ __launch_bounds__(256) void k_split_x(const float* __restrict__ X,
                                                 bf16_t* __restrict__ H,
                                                 bf16_t* __restrict__ L, int n) {
    int i = (blockIdx.x * 256 + threadIdx.x) * 4;
    if (i >= n) return;
    float4 v = *(const float4*)(X + i);
    float vv[4] = {v.x, v.y, v.z, v.w};
    union { bf16_t b[4]; uint2 u; } hh, ll;
#pragma unroll
    for (int j = 0; j < 4; j++) {
        bf16_t h = (bf16_t)vv[j];
        hh.b[j] = h;
        ll.b[j] = (bf16_t)(vv[j] - (float)h);
    }
    *(uint2*)(H + i) = hh.u;
    *(uint2*)(L + i) = ll.u;
}

// ---------------- W[3,512,512] -> WT[3,512(o),512(d)] split ----------------
__global__ __launch_bounds__(256) void k_split_wt(const float* __restrict__ W,
                                                  bf16_t* __restrict__ H,
                                                  bf16_t* __restrict__ L) {
    int t = blockIdx.x * 256 + threadIdx.x;
    int base = t * 4;
    int m = base >> 18;
    int o = (base >> 9) & 511;
    int d = base & 511;
    union { bf16_t b[4]; uint2 u; } hh, ll;
#pragma unroll
    for (int j = 0; j < 4; j++) {
        float w = W[m * 262144 + (d + j) * 512 + o];
        bf16_t h = (bf16_t)w;
        hh.b[j] = h;
        ll.b[j] = (bf16_t)(w - (float)h);
    }
    *(uint2*)(H + base) = hh.u;
    *(uint2*)(L + base) = ll.u;
}

// -------- QKV projection GEMM-NT, 128x128 tile, BK=32, split bf16x3 --------
__global__ __launch_bounds__(256) void k_qkv(
    const bf16_t* __restrict__ Ah, const bf16_t* __restrict__ Al,
    const bf16_t* __restrict__ Bh, const bf16_t* __restrict__ Bl,
    bf16_t* __restrict__ Qh, bf16_t* __restrict__ Ql,
    bf16_t* __restrict__ Kh, bf16_t* __restrict__ Kl,
    bf16_t* __restrict__ VT) {
    __shared__ bf16_t lds[16384];
    bf16_t* As_h = lds;
    bf16_t* Bs_h = lds + 4096;
    bf16_t* As_l = lds + 8192;
    bf16_t* Bs_l = lds + 12288;

    const int tid = threadIdx.x;
    const int lane = tid & 63;
    const int wid = tid >> 6;
    const int wr = wid >> 1, wc = wid & 1;
    const size_t i0 = (size_t)blockIdx.y * 128;
    const size_t j0 = (size_t)blockIdx.x * 128;

    const bf16_t* pAh = Ah + i0 * 512;
    const bf16_t* pBh = Bh + j0 * 512;
    const bf16_t* pAl = Al + i0 * 512;
    const bf16_t* pBl = Bl + j0 * 512;

    const int srow = tid >> 2;
    const int scoff = (tid & 3) * 8;

    f32x4 acc[4][4] = {};

    const int arow = wr * 64 + (lane & 15);
    const int brow = wc * 64 + (lane & 15);
    const int ko = (lane >> 4) * 8;

    for (int kt = 0; kt < 512; kt += 32) {
#pragma unroll
        for (int c = 0; c < 2; c++) {
            const size_t ra = (size_t)(c * 64 + srow) * 512 + kt + scoff;
            const int loff = c * 2048 + tid * 8;
            gload_lds16(pAh + ra, As_h + loff);
            gload_lds16(pBh + ra, Bs_h + loff);
            gload_lds16(pAl + ra, As_l + loff);
            gload_lds16(pBl + ra, Bs_l + loff);
        }
        __syncthreads();

        bf16x8 ah[4], bh[4], al[4], bl[4];
#pragma unroll
        for (int m = 0; m < 4; m++) ah[m] = *(const bf16x8*)&As_h[(arow + m * 16) * 32 + ko];
#pragma unroll
        for (int n = 0; n < 4; n++) bh[n] = *(const bf16x8*)&Bs_h[(brow + n * 16) * 32 + ko];
#pragma unroll
        for (int m = 0; m < 4; m++) al[m] = *(const bf16x8*)&As_l[(arow + m * 16) * 32 + ko];
#pragma unroll
        for (int n = 0; n < 4; n++) bl[n] = *(const bf16x8*)&Bs_l[(brow + n * 16) * 32 + ko];
        __builtin_amdgcn_s_setprio(1);
#pragma unroll
        for (int m = 0; m < 4; m++)
#pragma unroll
            for (int n = 0; n < 4; n++) {
                acc[m][n] = __builtin_amdgcn_mfma_f32_16x16x32_bf16(ah[m], bh[n], acc[m][n], 0, 0, 0);
                acc[m][n] = __builtin_amdgcn_mfma_f32_16x16x32_bf16(ah[m], bl[n], acc[m][n], 0, 0, 0);
                acc[m][n] = __builtin_amdgcn_mfma_f32_16x16x32_bf16(al[m], bh[n], acc[m][n], 0, 0, 0);
            }
        __builtin_amdgcn_s_setprio(0);
        __syncthreads();
    }

#pragma unroll
    for (int m = 0; m < 4; m++) {
#pragma unroll
        for (int n = 0; n < 4; n++) {
#pragma unroll
            for (int j = 0; j < 4; j++) {
                const size_t gr = i0 + wr * 64 + m * 16 + (lane >> 4) * 4 + j;
                const size_t gc = j0 + wc * 64 + n * 16 + (lane & 15);
                float v = acc[m][n][j];
                const int mat = (int)(gc >> 9);
                const size_t bloc = gr >> 11;
                const size_t nrow = gr & 2047;
                const size_t o = gc & 511;
                const size_t idx = bloc * 1048576 + nrow * 512 + o;
                if (mat == 0) {
                    float v2 = v * QSCALE;
                    bf16_t h = (bf16_t)v2;
                    Qh[idx] = h; Ql[idx] = (bf16_t)(v2 - (float)h);
                } else if (mat == 1) {
                    bf16_t h = (bf16_t)v;
                    Kh[idx] = h; Kl[idx] = (bf16_t)(v - (float)h);
                } else {
                    VT[bloc * 1048576 + o * 2048 + nrow] = (bf16_t)v;
                }
            }
        }
    }
}

// ---------------- fused flash attention ----------------
// Grid (32, G). Block 512 thr / 8 waves. QBLK=64 rows, KV tiles of 64.
// XCD-aware swizzle: hw linear id f -> f' = (f%8)*(total/8)+f/8 so all 32
// q-tiles of one batch co-reside on one XCD (K/V become L2-resident).
#define QK0_OFF 0
#define VT_OFF  65536
#define PT_OFF  131072
#define MP_OFF  139264
#define SP_OFF  139776
#define MR_OFF  140288

__global__ __launch_bounds__(512) void k_flash(
    const bf16_t* __restrict__ Qh, const bf16_t* __restrict__ Ql,
    const bf16_t* __restrict__ Kh, const bf16_t* __restrict__ Kl,
    const bf16_t* __restrict__ VT, float* __restrict__ Out) {
    __shared__ __align__(16) char smem[140800];

    const int tid = threadIdx.x;
    const int l = tid & 63, wid = tid >> 6;
    const int l15 = l & 15, l4 = l >> 4;
    const int rg4 = wid >> 1, kg = wid & 1;
    const int rg2 = wid >> 2, cg = wid & 3;

    // ---- XCD swizzle ----
    const int total = gridDim.x * gridDim.y;      // 32 * G, divisible by 8
    const int f = blockIdx.x + gridDim.x * blockIdx.y;  // hw linear id
    const int fp = (f & 7) * (total >> 3) + (f >> 3);
    const int b = fp >> 5;
    const int q0 = (fp & 31) * 64;
    const size_t NB = 1048576;

    const bf16_t* qhb = Qh + (size_t)b * NB;
    const bf16_t* qlb = Ql + (size_t)b * NB;
    const bf16_t* khb = Kh + (size_t)b * NB;
    const bf16_t* klb = Kl + (size_t)b * NB;
    const bf16_t* vtb = VT + (size_t)b * NB;

    float* MP = (float*)(smem + MP_OFF);   // [2][64] tile-max partials
    float* SP = (float*)(smem + SP_OFF);   // [2][64] exp-sum partials
    float* MR = (float*)(smem + MR_OFF);   // [2][64] running max, ping-pong

    if (tid < 128) MR[tid] = -3e38f;

    f32x4 O[2][8] = {};            // [mf][nf] 16-row x 16-col frags
    float mreg[2][4], lreg[2][4];
#pragma unroll
    for (int mf = 0; mf < 2; mf++)
#pragma unroll
        for (int j = 0; j < 4; j++) { mreg[mf][j] = -3e38f; lreg[mf][j] = 0.f; }

    const int srow = tid >> 3;          // staging row 0..63
    const int sgl = (tid & 7) ^ (srow & 7);  // swizzled source granule
    const int gsw = l15 & 7;            // frag-read swizzle key

    auto stage_chunk = [&](int t, int kc, int b2) {
        const int co = kc * 64 + sgl * 8;
        const bf16_t* qs = qhb + (size_t)(q0 + srow) * 512 + co;
        const bf16_t* qs2 = qlb + (size_t)(q0 + srow) * 512 + co;
        const bf16_t* ks = khb + (size_t)(t * 64 + srow) * 512 + co;
        const bf16_t* ks2 = klb + (size_t)(t * 64 + srow) * 512 + co;
        bf16_t* d = (bf16_t*)(smem + QK0_OFF + b2 * 32768 + tid * 16);
        gload_lds16(qs, d);
        gload_lds16(qs2, d + 4096);
        gload_lds16(ks, d + 8192);
        gload_lds16(ks2, d + 12288);
    };
    auto stage_v = [&](int t, int j) {
        const int g = j * 512 + tid;
        const int orow = g >> 3;
        const int gl = (g & 7) ^ (orow & 7);
        gload_lds16(vtb + (size_t)orow * 2048 + t * 64 + gl * 8,
                    (bf16_t*)(smem + VT_OFF + g * 16));
    };

    stage_chunk(0, 0, 0);

    for (int t = 0; t < 32; t++) {
        f32x4 S[2] = {};
#pragma unroll
        for (int kc = 0; kc < 8; kc++) {
            if (kc == 0)      asm volatile("s_waitcnt vmcnt(0) lgkmcnt(0)" ::: "memory");
            else if (kc == 7) asm volatile("s_waitcnt vmcnt(2)" ::: "memory");
            else              asm volatile("s_waitcnt vmcnt(1)" ::: "memory");
            asm volatile("s_barrier" ::: "memory");
            if (kc < 7) {
                stage_chunk(t, kc + 1, (kc + 1) & 1);
                stage_v(t, kc);
                if (kc == 6) stage_v(t, 7);
            } else if (t < 31) {
                stage_chunk(t + 1, 0, 0);
            }
            // compute chunk kc from buf kc&1
            const char* CB = smem + QK0_OFF + (kc & 1) * 32768;
            const int arow = rg4 * 16 + l15;
            __builtin_amdgcn_s_setprio(1);
#pragma unroll
            for (int ks = 0; ks < 2; ks++) {
                const int gph = ((ks * 4 + l4) ^ gsw) << 4;
                bf16x8 ah = *(const bf16x8*)(CB + arow * 128 + gph);
                bf16x8 al = *(const bf16x8*)(CB + 8192 + arow * 128 + gph);
#pragma unroll
                for (int nf = 0; nf < 2; nf++) {
                    const int brow = kg * 32 + nf * 16 + l15;
                    bf16x8 bh = *(const bf16x8*)(CB + 16384 + brow * 128 + gph);
                    bf16x8 bl = *(const bf16x8*)(CB + 24576 + brow * 128 + gph);
                    S[nf] = __builtin_amdgcn_mfma_f32_16x16x32_bf16(ah, bh, S[nf], 0, 0, 0);
                    S[nf] = __builtin_amdgcn_mfma_f32_16x16x32_bf16(ah, bl, S[nf], 0, 0, 0);
                    S[nf] = __builtin_amdgcn_mfma_f32_16x16x32_bf16(al, bh, S[nf], 0, 0, 0);
                }
            }
            __builtin_amdgcn_s_setprio(0);
        }

        // ---- online softmax (cross-wave via LDS) ----
        const int rb4 = rg4 * 16 + l4 * 4;
        float pm[4];
#pragma unroll
        for (int j = 0; j < 4; j++) pm[j] = fmaxf(S[0][j], S[1][j]);
#pragma unroll
        for (int off = 1; off < 16; off <<= 1)
#pragma unroll
            for (int j = 0; j < 4; j++) pm[j] = fmaxf(pm[j], __shfl_xor(pm[j], off));
        if (l15 == 0) {
            f32x4 v; v[0] = pm[0]; v[1] = pm[1]; v[2] = pm[2]; v[3] = pm[3];
            *(f32x4*)(MP + kg * 64 + rb4) = v;
        }
        asm volatile("s_waitcnt lgkmcnt(0)" ::: "memory");
        asm volatile("s_barrier" ::: "memory");

        f32x4 mp0 = *(const f32x4*)(MP + rb4);
        f32x4 mp1 = *(const f32x4*)(MP + 64 + rb4);
        f32x4 mold = *(const f32x4*)(MR + (t & 1) * 64 + rb4);
        float mnew[4];
#pragma unroll
        for (int j = 0; j < 4; j++) mnew[j] = fmaxf(mold[j], fmaxf(mp0[j], mp1[j]));
        if (kg == 0 && l15 == 0) {
            f32x4 v; v[0] = mnew[0]; v[1] = mnew[1]; v[2] = mnew[2]; v[3] = mnew[3];
            *(f32x4*)(MR + ((t + 1) & 1) * 64 + rb4) = v;
        }
        float p[2][4], ps[4];
#pragma unroll
        for (int nf = 0; nf < 2; nf++)
#pragma unroll
            for (int j = 0; j < 4; j++) p[nf][j] = exp2f((S[nf][j] - mnew[j]) * L2E);
#pragma unroll
        for (int j = 0; j < 4; j++) ps[j] = p[0][j] + p[1][j];
#pragma unroll
        for (int off = 1; off < 16; off <<= 1)
#pragma unroll
            for (int j = 0; j < 4; j++) ps[j] += __shfl_xor(ps[j], off);
        if (l15 == 0) {
            f32x4 v; v[0] = ps[0]; v[1] = ps[1]; v[2] = ps[2]; v[3] = ps[3];
            *(f32x4*)(SP + kg * 64 + rb4) = v;
        }
        // P -> bf16 into swizzled LDS tile
#pragma unroll
        for (int nf = 0; nf < 2; nf++)
#pragma unroll
            for (int j = 0; j < 4; j++) {
                const int row = rb4 + j;
                const int phys = (kg * 4 + nf * 2 + (l15 >> 3)) ^ (row & 7);
                *(bf16_t*)(smem + PT_OFF + row * 128 + phys * 16 + (l15 & 7) * 2) =
                    (bf16_t)p[nf][j];
            }
        if (t < 31) asm volatile("s_waitcnt vmcnt(4) lgkmcnt(0)" ::: "memory");
        else        asm volatile("s_waitcnt vmcnt(0) lgkmcnt(0)" ::: "memory");
        asm volatile("s_barrier" ::: "memory");

        // ---- PV: rescale O, accumulate P*V ----
#pragma unroll
        for (int mf = 0; mf < 2; mf++) {
            const int rb = rg2 * 32 + mf * 16 + l4 * 4;
            f32x4 mn = *(const f32x4*)(MR + ((t + 1) & 1) * 64 + rb);
            f32x4 sp0 = *(const f32x4*)(SP + rb);
            f32x4 sp1 = *(const f32x4*)(SP + 64 + rb);
            float fr[4];
#pragma unroll
            for (int j = 0; j < 4; j++) {
                fr[j] = exp2f((mreg[mf][j] - mn[j]) * L2E);
                lreg[mf][j] = lreg[mf][j] * fr[j] + sp0[j] + sp1[j];
                mreg[mf][j] = mn[j];
            }
#pragma unroll
            for (int nf = 0; nf < 8; nf++)
#pragma unroll
                for (int j = 0; j < 4; j++) O[mf][nf][j] *= fr[j];
        }
#pragma unroll
        for (int ks = 0; ks < 2; ks++) {
            const int gph = ((ks * 4 + l4) ^ gsw) << 4;
            bf16x8 pa[2];
#pragma unroll
            for (int mf = 0; mf < 2; mf++) {
                const int prow = rg2 * 32 + mf * 16 + l15;
                pa[mf] = *(const bf16x8*)(smem + PT_OFF + prow * 128 + gph);
            }
            __builtin_amdgcn_s_setprio(1);
#pragma unroll
            for (int nf = 0; nf < 8; nf++) {
                const int vrow = cg * 128 + nf * 16 + l15;
                bf16x8 vb = *(const bf16x8*)(smem + VT_OFF + vrow * 128 + gph);
#pragma unroll
                for (int mf = 0; mf < 2; mf++)
                    O[mf][nf] = __builtin_amdgcn_mfma_f32_16x16x32_bf16(pa[mf], vb, O[mf][nf], 0, 0, 0);
            }
            __builtin_amdgcn_s_setprio(0);
        }
    }

    // ---- epilogue: O / l ----
#pragma unroll
    for (int mf = 0; mf < 2; mf++) {
        float inv[4];
#pragma unroll
        for (int j = 0; j < 4; j++) inv[j] = 1.0f / lreg[mf][j];
#pragma unroll
        for (int nf = 0; nf < 8; nf++)
#pragma unroll
            for (int j = 0; j < 4; j++) {
                const size_t row = q0 + rg2 * 32 + mf * 16 + l4 * 4 + j;
                const size_t col = cg * 128 + nf * 16 + l15;
                Out[(size_t)b * NB + row * 512 + col] = O[mf][nf][j] * inv[j];
            }
    }
}

extern "C" void kernel_launch(void* const* d_in, const int* in_sizes, int n_in,
                              void* d_out, int out_size, void* d_ws, size_t ws_size,
                              hipStream_t stream) {
    const float* x = (const float*)d_in[0];
    const float* w = (const float*)d_in[1];
    float* out = (float*)d_out;

    const size_t NB = (size_t)2048 * 512;     // per-batch Q/K/V elems
    const size_t NW = (size_t)3 * 512 * 512;

    const size_t perG = 7 * NB * 2;
    size_t fixed = 2 * NW * 2 + 4096;
    int G = 1;
    if (ws_size > fixed + perG) {
        size_t g = (ws_size - fixed) / perG;
        G = (int)(g > 16 ? 16 : g);
    } else {
        return;  // workspace too small (needs ~17 MB)
    }

    size_t off = 0;
    char* wsb = (char*)d_ws;
    auto take = [&](size_t bytes) -> char* {
        char* p = wsb + off;
        off = (off + bytes + 255) & ~(size_t)255;
        return p;
    };
    bf16_t* wth = (bf16_t*)take(NW * 2);
    bf16_t* wtl = (bf16_t*)take(NW * 2);
    bf16_t* xh = (bf16_t*)take(G * NB * 2);
    bf16_t* xl = (bf16_t*)take(G * NB * 2);
    bf16_t* qh = (bf16_t*)take(G * NB * 2);
    bf16_t* ql = (bf16_t*)take(G * NB * 2);
    bf16_t* kh = (bf16_t*)take(G * NB * 2);
    bf16_t* kl = (bf16_t*)take(G * NB * 2);
    bf16_t* vt = (bf16_t*)take(G * NB * 2);

    k_split_wt<<<dim3((unsigned)(NW / 4 / 256)), 256, 0, stream>>>(w, wth, wtl);

    for (int g0 = 0; g0 < 16; g0 += G) {
        const int Gc = (16 - g0 < G) ? (16 - g0) : G;
        const size_t base = (size_t)g0 * NB;
        k_split_x<<<dim3((unsigned)(Gc * NB / 4 / 256)), 256, 0, stream>>>(
            x + base, xh, xl, (int)(Gc * NB));
        k_qkv<<<dim3(12, 16 * Gc), 256, 0, stream>>>(
            xh, xl, wth, wtl, qh, ql, kh, kl, vt);
        k_flash<<<dim3(32, Gc), 512, 0, stream>>>(
            qh, ql, kh, kl, vt, out + base);
    }
}